// Round 1
// baseline (281.457 us; speedup 1.0000x reference)
//
#include <hip/hip_runtime.h>

// loss = sum((input - target)^2) / (N/4), by Haar orthonormality.
// N = 4*32*512*512 = 33554432 elements per tensor; N/4 bands divisor = 8388608.

__global__ __launch_bounds__(256) void haar_mse_reduce(
    const float4* __restrict__ x,
    const float4* __restrict__ t,
    float* __restrict__ out,
    int n4)
{
    int idx = blockIdx.x * blockDim.x + threadIdx.x;
    int stride = gridDim.x * blockDim.x;

    float acc = 0.0f;
    for (int i = idx; i < n4; i += stride) {
        float4 a = x[i];
        float4 b = t[i];
        float dx = a.x - b.x;
        float dy = a.y - b.y;
        float dz = a.z - b.z;
        float dw = a.w - b.w;
        acc = fmaf(dx, dx, acc);
        acc = fmaf(dy, dy, acc);
        acc = fmaf(dz, dz, acc);
        acc = fmaf(dw, dw, acc);
    }

    // wave (64-lane) shuffle reduction
    #pragma unroll
    for (int off = 32; off > 0; off >>= 1)
        acc += __shfl_down(acc, off, 64);

    __shared__ float wave_sums[4];  // 256 threads = 4 waves
    int wave = threadIdx.x >> 6;
    int lane = threadIdx.x & 63;
    if (lane == 0) wave_sums[wave] = acc;
    __syncthreads();

    if (threadIdx.x == 0) {
        float s = wave_sums[0] + wave_sums[1] + wave_sums[2] + wave_sums[3];
        // pre-scale so the atomic accumulates at magnitude ~8 (tiny ulp)
        atomicAdd(out, s * (1.0f / 8388608.0f));
    }
}

extern "C" void kernel_launch(void* const* d_in, const int* in_sizes, int n_in,
                              void* d_out, int out_size, void* d_ws, size_t ws_size,
                              hipStream_t stream) {
    const float* x = (const float*)d_in[0];
    const float* t = (const float*)d_in[1];
    float* out = (float*)d_out;

    int n = in_sizes[0];          // 33554432
    int n4 = n / 4;               // float4 count: 8388608

    // d_out is poisoned (0xAA) before every timed launch — zero it on-stream.
    hipMemsetAsync(out, 0, sizeof(float), stream);

    const int block = 256;
    const int grid = 2048;        // 524288 threads -> 16 float4s/thread/array
    haar_mse_reduce<<<grid, block, 0, stream>>>(
        (const float4*)x, (const float4*)t, out, n4);
}

// Round 2
// 278.512 us; speedup vs baseline: 1.0106x; 1.0106x over previous
//
#include <hip/hip_runtime.h>

// loss = sum((input - target)^2) / (N/4), by Haar orthonormality of the
// 2x2 transform (rows of H are orthonormal => sum of band MSEs == pixel MSE*4/N).
// N = 4*32*512*512 = 33554432; divisor = N/4 = 8388608.

__global__ __launch_bounds__(256) void haar_mse_reduce(
    const float4* __restrict__ x,
    const float4* __restrict__ t,
    float* __restrict__ out,
    int n4)
{
    const int idx = blockIdx.x * blockDim.x + threadIdx.x;
    const int stride = gridDim.x * blockDim.x;

    float acc0 = 0.0f, acc1 = 0.0f, acc2 = 0.0f, acc3 = 0.0f;

    int i = idx;
    // unroll-by-4: 8 independent loads in flight before any compute (MLP=8)
    for (; i + 3 * stride < n4; i += 4 * stride) {
        float4 a0 = x[i];
        float4 a1 = x[i + stride];
        float4 a2 = x[i + 2 * stride];
        float4 a3 = x[i + 3 * stride];
        float4 b0 = t[i];
        float4 b1 = t[i + stride];
        float4 b2 = t[i + 2 * stride];
        float4 b3 = t[i + 3 * stride];

        float d;
        d = a0.x - b0.x; acc0 = fmaf(d, d, acc0);
        d = a0.y - b0.y; acc0 = fmaf(d, d, acc0);
        d = a0.z - b0.z; acc0 = fmaf(d, d, acc0);
        d = a0.w - b0.w; acc0 = fmaf(d, d, acc0);

        d = a1.x - b1.x; acc1 = fmaf(d, d, acc1);
        d = a1.y - b1.y; acc1 = fmaf(d, d, acc1);
        d = a1.z - b1.z; acc1 = fmaf(d, d, acc1);
        d = a1.w - b1.w; acc1 = fmaf(d, d, acc1);

        d = a2.x - b2.x; acc2 = fmaf(d, d, acc2);
        d = a2.y - b2.y; acc2 = fmaf(d, d, acc2);
        d = a2.z - b2.z; acc2 = fmaf(d, d, acc2);
        d = a2.w - b2.w; acc2 = fmaf(d, d, acc2);

        d = a3.x - b3.x; acc3 = fmaf(d, d, acc3);
        d = a3.y - b3.y; acc3 = fmaf(d, d, acc3);
        d = a3.z - b3.z; acc3 = fmaf(d, d, acc3);
        d = a3.w - b3.w; acc3 = fmaf(d, d, acc3);
    }
    // tail (not taken for the fixed 8388608 / 524288-thread shape)
    for (; i < n4; i += stride) {
        float4 a = x[i];
        float4 b = t[i];
        float d;
        d = a.x - b.x; acc0 = fmaf(d, d, acc0);
        d = a.y - b.y; acc1 = fmaf(d, d, acc1);
        d = a.z - b.z; acc2 = fmaf(d, d, acc2);
        d = a.w - b.w; acc3 = fmaf(d, d, acc3);
    }

    float acc = (acc0 + acc1) + (acc2 + acc3);

    // wave (64-lane) shuffle reduction
    #pragma unroll
    for (int off = 32; off > 0; off >>= 1)
        acc += __shfl_down(acc, off, 64);

    __shared__ float wave_sums[4];  // 256 threads = 4 waves
    const int wave = threadIdx.x >> 6;
    const int lane = threadIdx.x & 63;
    if (lane == 0) wave_sums[wave] = acc;
    __syncthreads();

    if (threadIdx.x == 0) {
        float s = (wave_sums[0] + wave_sums[1]) + (wave_sums[2] + wave_sums[3]);
        // pre-scale so the atomic accumulates at magnitude ~8 (tiny ulp error)
        atomicAdd(out, s * (1.0f / 8388608.0f));
    }
}

extern "C" void kernel_launch(void* const* d_in, const int* in_sizes, int n_in,
                              void* d_out, int out_size, void* d_ws, size_t ws_size,
                              hipStream_t stream) {
    const float* x = (const float*)d_in[0];
    const float* t = (const float*)d_in[1];
    float* out = (float*)d_out;

    int n = in_sizes[0];          // 33554432
    int n4 = n / 4;               // float4 count: 8388608

    // d_out is poisoned (0xAA) before every timed launch — zero it on-stream.
    hipMemsetAsync(out, 0, sizeof(float), stream);

    const int block = 256;
    const int grid = 2048;        // 8192 waves = full residency on 256 CUs
    haar_mse_reduce<<<grid, block, 0, stream>>>(
        (const float4*)x, (const float4*)t, out, n4);
}